// Round 8
// baseline (281.914 us; speedup 1.0000x reference)
//
#include <hip/hip_runtime.h>
#include <hip/hip_bf16.h>
#include <cstdint>

typedef __bf16 bf16x8 __attribute__((ext_vector_type(8)));
typedef float  f32x4  __attribute__((ext_vector_type(4)));
typedef unsigned short u16x8 __attribute__((ext_vector_type(8)));

__device__ __forceinline__ unsigned short f2bf(float f) {
  __hip_bfloat16 h = __float2bfloat16(f);
  return __builtin_bit_cast(unsigned short, h);
}
__device__ __forceinline__ float bf2f(unsigned short u) {
  return __builtin_bit_cast(float, (unsigned)u << 16);
}

#define GL2LDS16(gp, lp)                                                      \
  __builtin_amdgcn_global_load_lds(                                           \
      (const __attribute__((address_space(1))) unsigned int*)(gp),            \
      (__attribute__((address_space(3))) unsigned int*)(lp), 16, 0, 0)

#define SBAR                                                                  \
  {                                                                           \
    __builtin_amdgcn_s_barrier();                                             \
    __builtin_amdgcn_sched_barrier(0);                                        \
  }
#define WAITV(n)                                                              \
  {                                                                           \
    asm volatile("s_waitcnt vmcnt(" #n ")" ::: "memory");                     \
    __builtin_amdgcn_sched_barrier(0);                                        \
  }
#define WAITL0                                                                \
  {                                                                           \
    asm volatile("s_waitcnt lgkmcnt(0)" ::: "memory");                        \
    __builtin_amdgcn_sched_barrier(0);                                        \
  }

// 128x256-tile GEMM, C[m][n] = sum_k A[m][k]*B[n][k] (B transposed layout).
// BK=32, 8 waves (2Mx4N), per-wave 64x64 = acc[4][4] 16x16 frags.
// LDS: 3-slot ring x 24KB (A 8KB + B 16KB) = 72KB -> 2 BLOCKS/CU (the R7
// fix: previous 128KB tiles forced 1 block/CU = 2 waves/SIMD, so vmcnt
// stalls had no other wave to hide under; 16 waves/CU restores the m97/m114
// implicit overlap).
// Per K-tile (single barrier, R5-verified template, lookahead-2):
//   {stage(t+2): 3 gl2lds; 8 ds_read(t); lgkm0; 16 MFMA; vmcnt(3); s_barrier}
// FIFO: entering t, 3 outstanding (t+1's); stage -> 6; vmcnt(3) retires
// t+1's. Overwrite safety: slot (t+2)%3 was read in t-1, lgkm0-retired
// before t-1's end barrier. Never vmcnt(0) in the loop.
// Swizzle phys = l ^ (((l>>7)&3)<<4) on BOTH pre-swizzled global source and
// ds_read address (period-8-row involution; measured 0 bank conflicts).
// Modes: 0 proj (col bias + elu+1, bf16)     [Qp, Kp]
//        3 split-K DxD partial, z=ks*4+b, K-window b*4096+ks*1024  [M=Kp^T x]
//        5 split-K KVt partial: A k-window ks*256; B=M[b] + k-window [WvT.M^T]
//        4 numerator (f32 out, /norm[row])
template <int MODE>
__global__ __launch_bounds__(512, 4) void gemm128(
    const unsigned short* __restrict__ A, long long lda, long long aOffZ,
    const unsigned short* __restrict__ B, long long ldb, long long bOffZ,
    void* __restrict__ C, long long ldc, long long cOffZ,
    const float* __restrict__ bias, const float* __restrict__ norm,
    long long normOffZ, int K) {
  __shared__ __attribute__((aligned(16))) char lds[3 * 24576];
  const int t = threadIdx.x;
  const int wave = t >> 6, lane = t & 63;
  const int wm = wave >> 2, wn = wave & 3;
  const int fr = lane & 15, fq = lane >> 4;

  // bijective XCD swizzle on flat xy block id (all grids here are %8==0)
  const int gx = gridDim.x, gy = gridDim.y;
  int flat = blockIdx.y * gx + blockIdx.x;
  const int total = gx * gy;
  if ((total & 7) == 0) flat = (flat & 7) * (total >> 3) + (flat >> 3);
  const int bx = flat % gx, by = flat / gx;
  const int m0 = by * 128, n0 = bx * 256;

  const long long z = blockIdx.z;
  long long aBase, bBase;
  if (MODE == 3) {
    const long long koff = (z & 3) * 4096 + (z >> 2) * 1024;
    aBase = koff;
    bBase = koff;
  } else if (MODE == 5) {
    aBase = (z >> 2) * 256;
    bBase = (z & 3) * 1048576ll + (z >> 2) * 256;
  } else {
    aBase = z * aOffZ;
    bBase = z * bOffZ;
  }
  const unsigned short* Az = A + aBase;
  const unsigned short* Bz = B + bBase;

  // staging sources. A-sub 8KB: thread t's 16B lands at linear byte t*16;
  // B-sub 16KB: c*8192 + t*16. Content at phys d must be logical
  // l = d ^ (((d>>7)&3)<<4); row = l>>6 (64B rows), kel = (l&63)>>1.
  const unsigned short* gA;
  const unsigned short* gB[2];
  {
    int d = t * 16;
    int l = d ^ (((d >> 7) & 3) << 4);
    gA = Az + (long long)(m0 + (l >> 6)) * lda + ((l & 63) >> 1);
  }
#pragma unroll
  for (int c = 0; c < 2; ++c) {
    int d = c * 8192 + t * 16;
    int l = d ^ (((d >> 7) & 3) << 4);
    gB[c] = Bz + (long long)(n0 + (l >> 6)) * ldb + ((l & 63) >> 1);
  }

  // fragment read cores (swizzle folded; (row>>1)&3 is i-invariant mod 4)
  const int slotx = (fr >> 1) & 3;
  const int acore = wm * 4096 + fr * 64 + ((fq ^ slotx) << 4);
  const int bcore = 8192 + wn * 4096 + fr * 64 + ((fq ^ slotx) << 4);

  f32x4 acc[4][4];
#pragma unroll
  for (int i = 0; i < 4; ++i)
#pragma unroll
    for (int j = 0; j < 4; ++j) acc[i][j] = (f32x4){0.f, 0.f, 0.f, 0.f};

  const int NT = K >> 5;  // BK=32 K-tiles

  auto stage = [&](int tile) {
    char* sb = lds + (tile % 3) * 24576 + wave * 1024;
    const int k0 = tile << 5;
    GL2LDS16(gA + k0, sb);
    GL2LDS16(gB[0] + k0, sb + 8192);
    GL2LDS16(gB[1] + k0, sb + 16384);
  };

  stage(0);
  stage(1);
  WAITV(3);  // tile 0's 3 loads landed (tile 1's may be outstanding)
  SBAR;

  bf16x8 av[4], bv[4];
  for (int tt = 0; tt < NT - 2; ++tt) {
    const char* sb = lds + (tt % 3) * 24576;
    stage(tt + 2);  // slot (tt+2)%3 == (tt-1)%3, retired+barriered in tt-1
#pragma unroll
    for (int i = 0; i < 4; ++i) {
      av[i] = *(const bf16x8*)(sb + acore + i * 1024);
      bv[i] = *(const bf16x8*)(sb + bcore + i * 1024);
    }
    WAITL0;
    __builtin_amdgcn_s_setprio(1);
#pragma unroll
    for (int mi = 0; mi < 4; ++mi)
#pragma unroll
      for (int ni = 0; ni < 4; ++ni)
        acc[mi][ni] = __builtin_amdgcn_mfma_f32_16x16x32_bf16(
            av[mi], bv[ni], acc[mi][ni], 0, 0, 0);
    __builtin_amdgcn_s_setprio(0);
    WAITV(3);  // retire tile tt+1's loads; barrier globalizes
    SBAR;
  }

  // tail tt = NT-2 (slot staged long ago, already retired)
  {
    const char* sb = lds + ((NT - 2) % 3) * 24576;
#pragma unroll
    for (int i = 0; i < 4; ++i) {
      av[i] = *(const bf16x8*)(sb + acore + i * 1024);
      bv[i] = *(const bf16x8*)(sb + bcore + i * 1024);
    }
    WAITL0;
#pragma unroll
    for (int mi = 0; mi < 4; ++mi)
#pragma unroll
      for (int ni = 0; ni < 4; ++ni)
        acc[mi][ni] = __builtin_amdgcn_mfma_f32_16x16x32_bf16(
            av[mi], bv[ni], acc[mi][ni], 0, 0, 0);
    WAITV(0);  // tile NT-1's loads (staged by all waves) retired
    SBAR;
  }
  // tail tt = NT-1
  {
    const char* sb = lds + ((NT - 1) % 3) * 24576;
#pragma unroll
    for (int i = 0; i < 4; ++i) {
      av[i] = *(const bf16x8*)(sb + acore + i * 1024);
      bv[i] = *(const bf16x8*)(sb + bcore + i * 1024);
    }
    WAITL0;
#pragma unroll
    for (int mi = 0; mi < 4; ++mi)
#pragma unroll
      for (int ni = 0; ni < 4; ++ni)
        acc[mi][ni] = __builtin_amdgcn_mfma_f32_16x16x32_bf16(
            av[mi], bv[ni], acc[mi][ni], 0, 0, 0);
  }

  // C-write. C/D layout: col = lane&15, row = (lane>>4)*4 + j [m89-verified]
  const float* nrmz = (MODE == 4) ? (norm + z * normOffZ) : nullptr;
  float* Cf = (float*)C + z * cOffZ;
  unsigned short* Cu = (unsigned short*)C + z * cOffZ;
#pragma unroll
  for (int mi = 0; mi < 4; ++mi) {
    const int rbase = m0 + wm * 64 + mi * 16 + fq * 4;
    float nv[4];
#pragma unroll
    for (int j = 0; j < 4; ++j)
      if (MODE == 4) nv[j] = nrmz[rbase + j];
#pragma unroll
    for (int ni = 0; ni < 4; ++ni) {
      const int c = n0 + wn * 64 + ni * 16 + fr;
      float cb = 0.f;
      if (MODE == 0) cb = bias[c];
#pragma unroll
      for (int j = 0; j < 4; ++j) {
        float v = acc[mi][ni][j];
        if (MODE == 0) {
          v += cb;
          v = (v > 0.f) ? v + 1.f : __expf(v);
        }
        const long long ci = (long long)(rbase + j) * ldc + c;
        if (MODE == 4)
          Cf[ci] = v / nv[j];
        else
          Cu[ci] = f2bf(v);
      }
    }
  }
}

// bf16 transpose: in [16384][1024] -> out [1024][16384]. 64x64 tiles,
// chunk-XOR swizzled LDS (16B granules, conflict-reduced gather).
__global__ __launch_bounds__(256) void transpose_bf(
    const unsigned short* __restrict__ in, unsigned short* __restrict__ out) {
  __shared__ unsigned short tile[4096];
  const int t = threadIdx.x;
  const long long r0 = (long long)blockIdx.x * 64;  // input row (n)
  const long long c0 = (long long)blockIdx.y * 64;  // input col (k)
#pragma unroll
  for (int it = 0; it < 2; ++it) {
    const int id = it * 256 + t;
    const int r = id >> 3, cc = id & 7;
    const int pc = cc ^ ((r >> 3) & 7);
    *(u16x8*)&tile[r * 64 + pc * 8] =
        *(const u16x8*)&in[(r0 + r) * 1024 + c0 + cc * 8];
  }
  __syncthreads();
#pragma unroll
  for (int it = 0; it < 2; ++it) {
    const int id = it * 256 + t;
    const int c = id >> 3, r8 = (id & 7) * 8;
    const int pc = (c >> 3) ^ (r8 >> 3);
    u16x8 v;
#pragma unroll
    for (int j = 0; j < 8; ++j) v[j] = tile[(r8 + j) * 64 + pc * 8 + (c & 7)];
    *(u16x8*)&out[(c0 + c) * 16384 + r0 + r8] = v;
  }
}

// Out[b][e][d] = sum_ks P[ks*4+b][e][d]   (P: [16][1024][1024] bf16)
__global__ __launch_bounds__(256) void reduce_kvt(
    const unsigned short* __restrict__ P, unsigned short* __restrict__ Out) {
  const long long i = ((long long)blockIdx.x * 256 + threadIdx.x) * 8;
  const int b = (int)(i >> 20);
  const long long ed = i & ((1ll << 20) - 1);
  float s[8] = {0.f, 0.f, 0.f, 0.f, 0.f, 0.f, 0.f, 0.f};
#pragma unroll
  for (int ks = 0; ks < 4; ++ks) {
    u16x8 v = *(const u16x8*)(P + ((long long)(ks * 4 + b) << 20) + ed);
#pragma unroll
    for (int j = 0; j < 8; ++j) s[j] += bf2f(v[j]);
  }
  u16x8 o;
#pragma unroll
  for (int j = 0; j < 8; ++j) o[j] = f2bf(s[j]);
  *(u16x8*)(Out + i) = o;
}

// KVt[b][e][d] = sum_ks P[ks*4+b][e][d] + bv[e]*Ksum[b][d]
__global__ __launch_bounds__(256) void reduce_kvt_bias(
    const unsigned short* __restrict__ P, const float* __restrict__ bv,
    const float* __restrict__ Ksum, unsigned short* __restrict__ KVt) {
  const long long i = ((long long)blockIdx.x * 256 + threadIdx.x) * 8;
  const int b = (int)(i >> 20);
  const long long ed = i & ((1ll << 20) - 1);
  const int e = (int)(ed >> 10), d = (int)(ed & 1023);
  float s[8] = {0.f, 0.f, 0.f, 0.f, 0.f, 0.f, 0.f, 0.f};
#pragma unroll
  for (int ks = 0; ks < 4; ++ks) {
    u16x8 v = *(const u16x8*)(P + ((long long)(ks * 4 + b) << 20) + ed);
#pragma unroll
    for (int j = 0; j < 8; ++j) s[j] += bf2f(v[j]);
  }
  const float bve = bv[e];
  const float* kp = Ksum + b * 1024 + d;
  u16x8 o;
#pragma unroll
  for (int j = 0; j < 8; ++j) o[j] = f2bf(s[j] + bve * kp[j]);
  *(u16x8*)(KVt + i) = o;
}

// W [1024(in)][1024(out)] f32  ->  WT [1024(out)][1024(in)] bf16
__global__ __launch_bounds__(256) void transpose_w(
    const float* __restrict__ W, unsigned short* __restrict__ WT) {
  __shared__ float tile[32][33];
  const int tx = threadIdx.x & 31, ty = threadIdx.x >> 5;
  const int i0 = blockIdx.y * 32, o0 = blockIdx.x * 32;
#pragma unroll
  for (int s = 0; s < 32; s += 8)
    tile[ty + s][tx] = W[(long long)(i0 + ty + s) * 1024 + o0 + tx];
  __syncthreads();
#pragma unroll
  for (int s = 0; s < 32; s += 8)
    WT[(long long)(o0 + ty + s) * 1024 + i0 + tx] = f2bf(tile[tx][ty + s]);
}

__global__ __launch_bounds__(256) void convert_x(
    const float4* __restrict__ in, uint2* __restrict__ out, int n4) {
  const int stride = gridDim.x * blockDim.x;
  for (int i = blockIdx.x * blockDim.x + threadIdx.x; i < n4; i += stride) {
    float4 v = in[i];
    uint2 o;
    o.x = (unsigned)f2bf(v.x) | ((unsigned)f2bf(v.y) << 16);
    o.y = (unsigned)f2bf(v.z) | ((unsigned)f2bf(v.w) << 16);
    out[i] = o;
  }
}

// K_sum[b][d] = sum_n KpT[d][b*4096 + n]   (one wave per (b,d), u16x8 loads)
__global__ __launch_bounds__(256) void ksum_kernel(
    const unsigned short* __restrict__ KpT, float* __restrict__ Ksum) {
  const int gw = (blockIdx.x * 256 + threadIdx.x) >> 6;  // 0..4095
  const int lane = threadIdx.x & 63;
  const int d = gw >> 2, b = gw & 3;
  const unsigned short* p = KpT + (long long)d * 16384 + b * 4096 + lane * 8;
  float s = 0.f;
#pragma unroll
  for (int it = 0; it < 8; ++it) {
    u16x8 v = *(const u16x8*)(p + it * 512);
#pragma unroll
    for (int j = 0; j < 8; ++j) s += bf2f(v[j]);
  }
#pragma unroll
  for (int o = 32; o > 0; o >>= 1) s += __shfl_down(s, o, 64);
  if (lane == 0) Ksum[b * 1024 + d] = s;
}

// nrm[m] = eps + sum_d Qp[m][d] * Ksum[b][d]   (one wave per row m)
__global__ __launch_bounds__(256) void norm_kernel(
    const unsigned short* __restrict__ Qp, const float* __restrict__ Ksum,
    float* __restrict__ nrm) {
  const int gw = (blockIdx.x * 256 + threadIdx.x) >> 6;  // 0..16383
  const int lane = threadIdx.x & 63;
  const int b = gw >> 12;
  const unsigned short* q = Qp + (long long)gw * 1024 + lane * 8;
  const float* ks = Ksum + b * 1024 + lane * 8;
  float s = 0.f;
#pragma unroll
  for (int it = 0; it < 2; ++it) {
    u16x8 v = *(const u16x8*)(q + it * 512);
    float4 k0 = *(const float4*)(ks + it * 512);
    float4 k1 = *(const float4*)(ks + it * 512 + 4);
    s += bf2f(v[0]) * k0.x + bf2f(v[1]) * k0.y + bf2f(v[2]) * k0.z +
         bf2f(v[3]) * k0.w + bf2f(v[4]) * k1.x + bf2f(v[5]) * k1.y +
         bf2f(v[6]) * k1.z + bf2f(v[7]) * k1.w;
  }
#pragma unroll
  for (int o = 32; o > 0; o >>= 1) s += __shfl_down(s, o, 64);
  if (lane == 0) nrm[gw] = s + 1e-6f;
}

extern "C" void kernel_launch(void* const* d_in, const int* in_sizes, int n_in,
                              void* d_out, int out_size, void* d_ws,
                              size_t ws_size, hipStream_t stream) {
  const float* x  = (const float*)d_in[0];
  const float* Wq = (const float*)d_in[1];
  const float* bq = (const float*)d_in[2];
  const float* Wk = (const float*)d_in[3];
  const float* bk = (const float*)d_in[4];
  const float* Wv = (const float*)d_in[5];
  const float* bv = (const float*)d_in[6];
  float* out = (float*)d_out;

  const size_t MN = 16384ull * 1024ull;
  char* w = (char*)d_ws;
  unsigned short* R0 = (unsigned short*)w;  w += MN * 2;                 // xb, later KpT
  unsigned short* WT = (unsigned short*)w;  w += 3ull * 1024 * 1024 * 2; // WqT|WkT|WvT
  unsigned short* Qp = (unsigned short*)w;  w += MN * 2;                 // [16384][1024]
  unsigned short* R3 = (unsigned short*)w;  w += MN * 2;                 // Kp, later Pm/Pk2
  unsigned short* xbT = (unsigned short*)w; w += MN * 2;                 // [1024][16384]
  unsigned short* R5 = (unsigned short*)w;  w += 4ull * 1024 * 1024 * 2; // M, later KVt
  float* Ksum = (float*)w;  w += 4ull * 1024 * 4;
  float* nrm  = (float*)w;  w += 16384ull * 4;

  unsigned short* xb  = R0;
  unsigned short* Kp  = R3;
  unsigned short* KpT = R0;   // after transpose, xb is dead
  unsigned short* Pm  = R3;   // after KpT transpose, Kp is dead
  unsigned short* M   = R5;
  unsigned short* Pk2 = R3;   // after reduce_kvt, Pm is dead
  unsigned short* KVt = R5;   // after KV2 partials, M is dead

  transpose_w<<<dim3(32, 32), 256, 0, stream>>>(Wq, WT);
  transpose_w<<<dim3(32, 32), 256, 0, stream>>>(Wk, WT + 1024 * 1024);
  transpose_w<<<dim3(32, 32), 256, 0, stream>>>(Wv, WT + 2 * 1024 * 1024);
  convert_x<<<2048, 256, 0, stream>>>((const float4*)x, (uint2*)xb,
                                      (int)(MN / 4));
  transpose_bf<<<dim3(256, 16), 256, 0, stream>>>(xb, xbT);

  // Qp = elu(x@Wq + bq)+1 : [16384][1024]
  gemm128<0><<<dim3(4, 128, 1), 512, 0, stream>>>(
      xb, 1024, 0, WT, 1024, 0, Qp, 1024, 0, bq, nullptr, 0, 1024);
  // Kp = elu(x@Wk + bk)+1 : [16384][1024]
  gemm128<0><<<dim3(4, 128, 1), 512, 0, stream>>>(
      xb, 1024, 0, WT + 1024 * 1024, 1024, 0, Kp, 1024, 0, bk, nullptr, 0,
      1024);
  transpose_bf<<<dim3(256, 16), 256, 0, stream>>>(Kp, KpT);  // xb dead -> R0
  ksum_kernel<<<1024, 256, 0, stream>>>(KpT, Ksum);
  // M partials: Pm[ks*4+b][d][k] = sum_{n in win} KpT[d][n]*xbT[k][n]
  gemm128<3><<<dim3(4, 8, 16), 512, 0, stream>>>(
      KpT, 16384, 0, xbT, 16384, 0, Pm, 1024, 1024 * 1024, nullptr, nullptr,
      0, 1024);
  reduce_kvt<<<2048, 256, 0, stream>>>(Pm, M);  // M[b][d][k] = Kp^T x
  // KVt partials: Pk2[ks*4+b][e][d] = sum_{k in ks-win} WvT[e][k]*M[b][d][k]
  gemm128<5><<<dim3(4, 8, 16), 512, 0, stream>>>(
      WT + 2 * 1024 * 1024, 1024, 0, M, 1024, 0, Pk2, 1024, 1024 * 1024,
      nullptr, nullptr, 0, 256);
  reduce_kvt_bias<<<2048, 256, 0, stream>>>(Pk2, bv, Ksum, KVt);
  norm_kernel<<<4096, 256, 0, stream>>>(Qp, Ksum, nrm);
  // out[b][n][e] = (sum_d Qp[bn][d] * KVt[b][e][d]) / nrm[bn]
  gemm128<4><<<dim3(4, 32, 4), 512, 0, stream>>>(
      Qp, 1024, 4096ll * 1024, KVt, 1024, 1024 * 1024, out, 1024,
      4096ll * 1024, nullptr, nrm, 4096, 1024);
}

// Round 9
// 244.947 us; speedup vs baseline: 1.1509x; 1.1509x over previous
//
#include <hip/hip_runtime.h>
#include <hip/hip_bf16.h>
#include <cstdint>

typedef __bf16 bf16x8 __attribute__((ext_vector_type(8)));
typedef float  f32x4  __attribute__((ext_vector_type(4)));
typedef unsigned short u16x8 __attribute__((ext_vector_type(8)));

__device__ __forceinline__ unsigned short f2bf(float f) {
  __hip_bfloat16 h = __float2bfloat16(f);
  return __builtin_bit_cast(unsigned short, h);
}
__device__ __forceinline__ float bf2f(unsigned short u) {
  return __builtin_bit_cast(float, (unsigned)u << 16);
}

#define GL2LDS16(gp, lp)                                                      \
  __builtin_amdgcn_global_load_lds(                                           \
      (const __attribute__((address_space(1))) unsigned int*)(gp),            \
      (__attribute__((address_space(3))) unsigned int*)(lp), 16, 0, 0)

#define SBAR                                                                  \
  {                                                                           \
    __builtin_amdgcn_s_barrier();                                             \
    __builtin_amdgcn_sched_barrier(0);                                        \
  }
#define WAITV(n)                                                              \
  {                                                                           \
    asm volatile("s_waitcnt vmcnt(" #n ")" ::: "memory");                     \
    __builtin_amdgcn_sched_barrier(0);                                        \
  }
#define WAITL0                                                                \
  {                                                                           \
    asm volatile("s_waitcnt lgkmcnt(0)" ::: "memory");                        \
    __builtin_amdgcn_sched_barrier(0);                                        \
  }

// 256x256-tile GEMM, C[m][n] = sum_k A[m][k]*B[n][k] (B transposed layout).
// R9 change: 16 WAVES (1024 threads), per-wave 64x64 (4Mx4N), BK=32,
// 3-slot LDS ring x 32KB = 96KB. Keeps the 256^2 tile's traffic (R8's
// 128x256 retile blew FETCH 50->174MB) while doubling waves/SIMD 2->4
// (acc[4][4] compiles to ~60 VGPR; 16 waves/CU fits under the 128-VGPR
// 4-wave/SIMD budget). LDS-read (~1500cy/tile) and MFMA (~1030cy/tile)
// are different pipes; 4 waves/SIMD gives the scheduler bodies to overlap
// them - the TLP that 2 waves/SIMD lacked (R5-R7 MfmaUtil pinned at 25%).
// Per K-tile (single barrier, R8-verified semantics, lookahead-2):
//   {stage(t+2): 2 gl2lds; 8 ds_read(t); lgkm0; 16 MFMA; vmcnt(2); s_barrier}
// FIFO: entering t, 2 outstanding (t+1's); stage -> 4; vmcnt(2) retires
// t+1's. Overwrite safety: slot (t+2)%3 was last read in t-1, lgkm0-retired
// before t-1's end barrier. Never vmcnt(0) in the loop.
// Swizzle phys = l ^ (((l>>7)&3)<<4) on BOTH pre-swizzled global source and
// ds_read address (involution; measured 0 bank conflicts).
// Modes: 0 proj (col bias + elu+1, bf16)                      [Qp]
//        1 merged KV-proj (rows<1024: +bk, elu+1 -> KpT; else +bv -> VT)
//        3 split-K KVt partial (z=ks*4+b; K-window b*4096+ks*1024)
//        4 numerator (f32 out, /norm[row])
template <int MODE>
__global__ __launch_bounds__(1024, 4) void gemm256w(
    const unsigned short* __restrict__ A, long long lda, long long aOffZ,
    const unsigned short* __restrict__ B, long long ldb, long long bOffZ,
    void* __restrict__ C, long long ldc, long long cOffZ,
    const float* __restrict__ bias, const float* __restrict__ bias2,
    const float* __restrict__ norm, long long normOffZ, int K) {
  __shared__ __attribute__((aligned(16))) char lds[3 * 32768];
  const int t = threadIdx.x;
  const int wave = t >> 6, lane = t & 63;
  const int wm = wave >> 2, wn = wave & 3;  // 4M x 4N waves
  const int fr = lane & 15, fq = lane >> 4;

  // bijective XCD swizzle on flat xy block id (all grids here are %8==0)
  const int gx = gridDim.x, gy = gridDim.y;
  int flat = blockIdx.y * gx + blockIdx.x;
  const int total = gx * gy;
  if ((total & 7) == 0) flat = (flat & 7) * (total >> 3) + (flat >> 3);
  int bx, by;
  if (MODE == 1) {  // column-major decode: XCD owns few bx across all by
    bx = flat / gy;
    by = flat - bx * gy;
  } else {
    bx = flat % gx;
    by = flat / gx;
  }
  const int m0 = by * 256, n0 = bx * 256;

  const long long z = blockIdx.z;
  long long aBase, bBase;
  if (MODE == 3) {
    const long long koff = (z & 3) * 4096 + (z >> 2) * 1024;
    aBase = koff;
    bBase = koff;
  } else {
    aBase = z * aOffZ;
    bBase = z * bOffZ;
  }
  const unsigned short* Az = A + aBase;
  const unsigned short* Bz = B + bBase;

  // staging: thread t's 16B lands at linear sub-tile byte d = t*16 (16KB
  // sub-tile, 1024 threads); content there must be logical l = d^swz.
  const unsigned short* gA;
  const unsigned short* gB;
  {
    int d = t * 16;
    int l = d ^ (((d >> 7) & 3) << 4);
    int row = l >> 6, kel = (l & 63) >> 1;
    gA = Az + (long long)(m0 + row) * lda + kel;
    gB = Bz + (long long)(n0 + row) * ldb + kel;
  }

  // fragment read cores (swizzle folded; (row>>1)&3 == (fr>>1)&3)
  const int slotx = (fr >> 1) & 3;
  const int acore = wm * 4096 + fr * 64 + ((fq ^ slotx) << 4);
  const int bcore = 16384 + wn * 4096 + fr * 64 + ((fq ^ slotx) << 4);

  f32x4 acc[4][4];
#pragma unroll
  for (int i = 0; i < 4; ++i)
#pragma unroll
    for (int j = 0; j < 4; ++j) acc[i][j] = (f32x4){0.f, 0.f, 0.f, 0.f};

  const int NT = K >> 5;  // BK=32 K-tiles

  auto stage = [&](int tile) {
    char* sb = lds + (tile % 3) * 32768 + wave * 1024;
    const int k0 = tile << 5;
    GL2LDS16(gA + k0, sb);
    GL2LDS16(gB + k0, sb + 16384);
  };

  stage(0);
  stage(1);
  WAITV(2);  // tile 0's 2 loads landed (tile 1's may be outstanding)
  SBAR;

  bf16x8 av[4], bv[4];
  for (int tt = 0; tt < NT - 2; ++tt) {
    const char* sb = lds + (tt % 3) * 32768;
    stage(tt + 2);  // slot (tt+2)%3 == (tt-1)%3: retired+barriered in tt-1
#pragma unroll
    for (int i = 0; i < 4; ++i) {
      av[i] = *(const bf16x8*)(sb + acore + i * 1024);
      bv[i] = *(const bf16x8*)(sb + bcore + i * 1024);
    }
    WAITL0;  // own ds_reads retired (stage-safety requires this pre-barrier)
    __builtin_amdgcn_s_setprio(1);
#pragma unroll
    for (int mi = 0; mi < 4; ++mi)
#pragma unroll
      for (int ni = 0; ni < 4; ++ni)
        acc[mi][ni] = __builtin_amdgcn_mfma_f32_16x16x32_bf16(
            av[mi], bv[ni], acc[mi][ni], 0, 0, 0);
    __builtin_amdgcn_s_setprio(0);
    WAITV(2);  // retire tile tt+1's loads; barrier globalizes
    SBAR;
  }

  // tail tt = NT-2
  {
    const char* sb = lds + ((NT - 2) % 3) * 32768;
#pragma unroll
    for (int i = 0; i < 4; ++i) {
      av[i] = *(const bf16x8*)(sb + acore + i * 1024);
      bv[i] = *(const bf16x8*)(sb + bcore + i * 1024);
    }
    WAITL0;
#pragma unroll
    for (int mi = 0; mi < 4; ++mi)
#pragma unroll
      for (int ni = 0; ni < 4; ++ni)
        acc[mi][ni] = __builtin_amdgcn_mfma_f32_16x16x32_bf16(
            av[mi], bv[ni], acc[mi][ni], 0, 0, 0);
    WAITV(0);  // tile NT-1's loads retired
    SBAR;
  }
  // tail tt = NT-1
  {
    const char* sb = lds + ((NT - 1) % 3) * 32768;
#pragma unroll
    for (int i = 0; i < 4; ++i) {
      av[i] = *(const bf16x8*)(sb + acore + i * 1024);
      bv[i] = *(const bf16x8*)(sb + bcore + i * 1024);
    }
    WAITL0;
#pragma unroll
    for (int mi = 0; mi < 4; ++mi)
#pragma unroll
      for (int ni = 0; ni < 4; ++ni)
        acc[mi][ni] = __builtin_amdgcn_mfma_f32_16x16x32_bf16(
            av[mi], bv[ni], acc[mi][ni], 0, 0, 0);
  }

  // C-write. C/D layout: col = lane&15, row = (lane>>4)*4 + j [m89-verified]
  const float* nrmz = (MODE == 4) ? (norm + z * normOffZ) : nullptr;
  float* Cf = (float*)C + z * cOffZ;
  unsigned short* Cu = (unsigned short*)C + z * cOffZ;
  const bool lower = (m0 < 1024);  // block-uniform (MODE 1: KpT vs VT half)
#pragma unroll
  for (int mi = 0; mi < 4; ++mi) {
    const int rbase = m0 + wm * 64 + mi * 16 + fq * 4;
    float rb[4], nv[4];
#pragma unroll
    for (int j = 0; j < 4; ++j) {
      if (MODE == 1)
        rb[j] = lower ? bias[rbase + j] : bias2[rbase - 1024 + j];
      if (MODE == 4) nv[j] = nrmz[rbase + j];
    }
#pragma unroll
    for (int ni = 0; ni < 4; ++ni) {
      const int c = n0 + wn * 64 + ni * 16 + fr;
      float cb = 0.f;
      if (MODE == 0) cb = bias[c];
#pragma unroll
      for (int j = 0; j < 4; ++j) {
        float v = acc[mi][ni][j];
        if (MODE == 0) v += cb;
        if (MODE == 1) v += rb[j];
        if (MODE == 0 || (MODE == 1 && lower))
          v = (v > 0.f) ? v + 1.f : __expf(v);
        const long long ci = (long long)(rbase + j) * ldc + c;
        if (MODE == 4)
          Cf[ci] = v / nv[j];
        else
          Cu[ci] = f2bf(v);
      }
    }
  }
}

// KVt[b][e][d] = sum_ks P[ks*4+b][e][d]   (P: [16][1024][1024] bf16 partials)
__global__ __launch_bounds__(256) void reduce_kvt(
    const unsigned short* __restrict__ P, unsigned short* __restrict__ KVt) {
  const long long i = ((long long)blockIdx.x * 256 + threadIdx.x) * 8;
  const int b = (int)(i >> 20);
  const long long ed = i & ((1ll << 20) - 1);
  float s[8] = {0.f, 0.f, 0.f, 0.f, 0.f, 0.f, 0.f, 0.f};
#pragma unroll
  for (int ks = 0; ks < 4; ++ks) {
    u16x8 v = *(const u16x8*)(P + ((long long)(ks * 4 + b) << 20) + ed);
#pragma unroll
    for (int j = 0; j < 8; ++j) s[j] += bf2f(v[j]);
  }
  u16x8 o;
#pragma unroll
  for (int j = 0; j < 8; ++j) o[j] = f2bf(s[j]);
  *(u16x8*)(KVt + i) = o;
}

// W [1024(in)][1024(out)] f32  ->  WT [1024(out)][1024(in)] bf16
__global__ __launch_bounds__(256) void transpose_w(
    const float* __restrict__ W, unsigned short* __restrict__ WT) {
  __shared__ float tile[32][33];
  const int tx = threadIdx.x & 31, ty = threadIdx.x >> 5;
  const int i0 = blockIdx.y * 32, o0 = blockIdx.x * 32;
#pragma unroll
  for (int s = 0; s < 32; s += 8)
    tile[ty + s][tx] = W[(long long)(i0 + ty + s) * 1024 + o0 + tx];
  __syncthreads();
#pragma unroll
  for (int s = 0; s < 32; s += 8)
    WT[(long long)(o0 + ty + s) * 1024 + i0 + tx] = f2bf(tile[tx][ty + s]);
}

__global__ __launch_bounds__(256) void convert_x(
    const float4* __restrict__ in, uint2* __restrict__ out, int n4) {
  const int stride = gridDim.x * blockDim.x;
  for (int i = blockIdx.x * blockDim.x + threadIdx.x; i < n4; i += stride) {
    float4 v = in[i];
    uint2 o;
    o.x = (unsigned)f2bf(v.x) | ((unsigned)f2bf(v.y) << 16);
    o.y = (unsigned)f2bf(v.z) | ((unsigned)f2bf(v.w) << 16);
    out[i] = o;
  }
}

// K_sum[b][d] = sum_n KpT[d][b*4096 + n]   (one wave per (b,d), u16x8 loads)
__global__ __launch_bounds__(256) void ksum_kernel(
    const unsigned short* __restrict__ KpT, float* __restrict__ Ksum) {
  const int gw = (blockIdx.x * 256 + threadIdx.x) >> 6;  // 0..4095
  const int lane = threadIdx.x & 63;
  const int d = gw >> 2, b = gw & 3;
  const unsigned short* p = KpT + (long long)d * 16384 + b * 4096 + lane * 8;
  float s = 0.f;
#pragma unroll
  for (int it = 0; it < 8; ++it) {
    u16x8 v = *(const u16x8*)(p + it * 512);
#pragma unroll
    for (int j = 0; j < 8; ++j) s += bf2f(v[j]);
  }
#pragma unroll
  for (int o = 32; o > 0; o >>= 1) s += __shfl_down(s, o, 64);
  if (lane == 0) Ksum[b * 1024 + d] = s;
}

// nrm[m] = eps + sum_d Qp[m][d] * Ksum[b][d]   (one wave per row m)
__global__ __launch_bounds__(256) void norm_kernel(
    const unsigned short* __restrict__ Qp, const float* __restrict__ Ksum,
    float* __restrict__ nrm) {
  const int gw = (blockIdx.x * 256 + threadIdx.x) >> 6;  // 0..16383
  const int lane = threadIdx.x & 63;
  const int b = gw >> 12;
  const unsigned short* q = Qp + (long long)gw * 1024 + lane * 8;
  const float* ks = Ksum + b * 1024 + lane * 8;
  float s = 0.f;
#pragma unroll
  for (int it = 0; it < 2; ++it) {
    u16x8 v = *(const u16x8*)(q + it * 512);
    float4 k0 = *(const float4*)(ks + it * 512);
    float4 k1 = *(const float4*)(ks + it * 512 + 4);
    s += bf2f(v[0]) * k0.x + bf2f(v[1]) * k0.y + bf2f(v[2]) * k0.z +
         bf2f(v[3]) * k0.w + bf2f(v[4]) * k1.x + bf2f(v[5]) * k1.y +
         bf2f(v[6]) * k1.z + bf2f(v[7]) * k1.w;
  }
#pragma unroll
  for (int o = 32; o > 0; o >>= 1) s += __shfl_down(s, o, 64);
  if (lane == 0) nrm[gw] = s + 1e-6f;
}

extern "C" void kernel_launch(void* const* d_in, const int* in_sizes, int n_in,
                              void* d_out, int out_size, void* d_ws,
                              size_t ws_size, hipStream_t stream) {
  const float* x  = (const float*)d_in[0];
  const float* Wq = (const float*)d_in[1];
  const float* bq = (const float*)d_in[2];
  const float* Wk = (const float*)d_in[3];
  const float* bk = (const float*)d_in[4];
  const float* Wv = (const float*)d_in[5];
  const float* bv = (const float*)d_in[6];
  float* out = (float*)d_out;

  const size_t MN = 16384ull * 1024ull;  // B*N*D elements
  char* w = (char*)d_ws;
  unsigned short* xb  = (unsigned short*)w;  w += MN * 2;                 // x bf16; dead after projections -> KVt partials [16][1024][1024]
  unsigned short* WT  = (unsigned short*)w;  w += 3ull * 1024 * 1024 * 2; // WqT|WkT|WvT bf16
  unsigned short* Qp  = (unsigned short*)w;  w += MN * 2;                 // [16384][1024]
  unsigned short* KVb = (unsigned short*)w;  w += 2 * MN * 2;            // [2048][16384]: rows 0-1023 KpT, 1024-2047 VT
  unsigned short* KVt = (unsigned short*)w;  w += 4ull * 1024 * 1024 * 2; // [4][1024(e)][1024(d)]
  float* Ksum = (float*)w;  w += 4ull * 1024 * 4;                         // [4][1024]
  float* nrm  = (float*)w;  w += 16384ull * 4;                            // [16384]
  unsigned short* Pkv = xb;  // split-K KVt partials, aliases dead xb
  unsigned short* KpT = KVb;
  unsigned short* VT  = KVb + MN;

  transpose_w<<<dim3(32, 32), 256, 0, stream>>>(Wq, WT);
  transpose_w<<<dim3(32, 32), 256, 0, stream>>>(Wk, WT + 1024 * 1024);
  transpose_w<<<dim3(32, 32), 256, 0, stream>>>(Wv, WT + 2 * 1024 * 1024);
  convert_x<<<2048, 256, 0, stream>>>((const float4*)x, (uint2*)xb,
                                      (int)(MN / 4));

  // Qp = elu(x @ Wq + bq)+1 : A=xb[16384][1024], Bt=WqT[1024][1024]
  gemm256w<0><<<dim3(4, 64, 1), 1024, 0, stream>>>(
      xb, 1024, 0, WT, 1024, 0, Qp, 1024, 0, bq, nullptr, nullptr, 0, 1024);
  // merged K/V projection: A=[WkT;WvT][2048][1024], Bt=xb[16384][1024]
  //   rows <1024: KpT = elu(.+bk)+1 ; rows >=1024: VT = . + bv
  gemm256w<1><<<dim3(64, 8, 1), 1024, 0, stream>>>(
      WT + 1024 * 1024, 1024, 0, xb, 1024, 0, KVb, 16384, 0, bk, bv, nullptr,
      0, 1024);
  ksum_kernel<<<1024, 256, 0, stream>>>(KpT, Ksum);
  // split-K KVt partials: z = ks*4+b; P[z] = VT[:,win] . KpT[:,win]^T
  gemm256w<3><<<dim3(4, 4, 16), 1024, 0, stream>>>(
      VT, 16384, 0, KpT, 16384, 0, Pkv, 1024, 1024 * 1024, nullptr, nullptr,
      nullptr, 0, 1024);
  reduce_kvt<<<2048, 256, 0, stream>>>(Pkv, KVt);
  norm_kernel<<<4096, 256, 0, stream>>>(Qp, Ksum, nrm);
  // out[b][n][e] = (sum_d Qp[bn][d] * KVt[b][e][d]) / nrm[bn]
  gemm256w<4><<<dim3(4, 16, 4), 1024, 0, stream>>>(
      Qp, 1024, 4096ll * 1024, KVt, 1024, 1024 * 1024, out, 1024,
      4096ll * 1024, nullptr, nullptr, nrm, 4096, 1024);
}